// Round 1
// baseline (1574.440 us; speedup 1.0000x reference)
//
#include <hip/hip_runtime.h>
#include <cstddef>

#define T_STEPS 512
#define BATCH   64
#define EDIM    512
#define HDIM    512
#define ODIM    512

#define HPAD    520   // hsm row stride (bf16): 16B-aligned, 2-way banks (free)
#define HALF    256

typedef __bf16 bf16;
typedef __bf16 bf16x4 __attribute__((ext_vector_type(4)));
typedef __bf16 bf16x8 __attribute__((ext_vector_type(8)));
typedef float  f32x4  __attribute__((ext_vector_type(4)));

// ---------------------------------------------------------------------------
// MFMA GEMM (round-5 proven): C[r,n] = sum_k X[r,k] * W[n, kw0+k] + bias[n]
// 128x128 tile, BK=32, 4 waves. Frag layouts proven r2/r4/r5.
// REMAP: store C with rows remapped  b*T+t  ->  t*B+b   ([B,T,*] -> [T,B,*])
// so the scan reads one contiguous [B,H] slab per timestep.
// ---------------------------------------------------------------------------
template <typename XT, bool REMAP>
__global__ __launch_bounds__(256) void gemm_mfma_kernel(
    const XT* __restrict__ X, int ldx,
    const float* __restrict__ W, int ldw, int kw0,
    const float* __restrict__ bias,
    float* __restrict__ C, int ldc, int K)
{
  __shared__ __align__(16) bf16 Asm[8 * 64 * 8];
  __shared__ __align__(16) bf16 Bsm[8 * 64 * 8];

  const int tid  = threadIdx.x;
  const int row0 = blockIdx.x * 128;
  const int col0 = blockIdx.y * 128;
  const int w    = tid >> 6, lane = tid & 63;
  const int q    = lane >> 4, nl = lane & 15;
  const int wm   = w >> 1, wn = w & 1;

  f32x4 acc[4][4] = {};

  for (int k0 = 0; k0 < K; k0 += 32) {
#pragma unroll
    for (int rep = 0; rep < 2; ++rep) {
      int idx = tid + rep * 256;
      int mt = idx >> 6, l2 = idx & 63;
      const XT* src = X + (size_t)(row0 + mt * 16 + (l2 & 15)) * ldx
                        + k0 + (l2 >> 4) * 8;
      bf16x8 v;
#pragma unroll
      for (int u = 0; u < 8; ++u) v[u] = (bf16)(float)src[u];
      *(bf16x8*)&Asm[(size_t)idx * 8] = v;
    }
#pragma unroll
    for (int rep = 0; rep < 2; ++rep) {
      int idx = tid + rep * 256;
      int nt = idx >> 6, l2 = idx & 63;
      const float* src = W + (size_t)(col0 + nt * 16 + (l2 & 15)) * ldw
                           + kw0 + k0 + (l2 >> 4) * 8;
      bf16x8 v;
#pragma unroll
      for (int u = 0; u < 8; ++u) v[u] = (bf16)src[u];
      *(bf16x8*)&Bsm[(size_t)idx * 8] = v;
    }
    __syncthreads();

    bf16x8 a[4], b[4];
#pragma unroll
    for (int i = 0; i < 4; ++i)
      a[i] = *(bf16x8*)&Asm[(size_t)((wm * 4 + i) * 64 + lane) * 8];
#pragma unroll
    for (int j = 0; j < 4; ++j)
      b[j] = *(bf16x8*)&Bsm[(size_t)((wn * 4 + j) * 64 + lane) * 8];
#pragma unroll
    for (int i = 0; i < 4; ++i)
#pragma unroll
      for (int j = 0; j < 4; ++j)
        acc[i][j] = __builtin_amdgcn_mfma_f32_16x16x32_bf16(a[i], b[j], acc[i][j], 0, 0, 0);
    __syncthreads();
  }

#pragma unroll
  for (int i = 0; i < 4; ++i)
#pragma unroll
    for (int j = 0; j < 4; ++j) {
      int colg = col0 + wn * 64 + j * 16 + nl;
#pragma unroll
      for (int r = 0; r < 4; ++r) {
        size_t rowg = (size_t)(row0 + wm * 64 + i * 16 + q * 4 + r);
        size_t crow = REMAP ? (((rowg & (T_STEPS - 1)) << 6) | (rowg >> 9)) : rowg;
        C[crow * ldc + colg] = acc[i][j][r] + bias[colg];
      }
    }
}

// ---------------------------------------------------------------------------
// SPLIT scan: 8 active blocks (2 per cluster of 16 batch rows; each block
// owns 256 of the 512 hidden columns). All of W1h for a block's half lives
// in registers: Wreg[2][16] = 128 VGPR/wave -> ZERO per-step W LDS reads.
// Per step (t>0):
//   poll peer flag >= t  ->  agent-scope loads of peer h_{t-1} half (L3)
//   MFMA own 8 K-tiles from hsm (locally produced last step)  [hides exchange]
//   stage peer half -> hsm, __syncthreads, MFMA peer 8 K-tiles
//   relu -> bf16x4: ds_write_b64 to hsm own half + 8B global store to Hbf
//   __syncthreads; tid0: threadfence + flag++   (round-4 proven protocol)
// Operand-swapped MFMA:  mfma(Wfrag, hfrag, acc) => D[n][m]; lane (q,nl)
// holds out[n = n0 + q*4 + r][m = nl]  ->  4 consecutive columns per lane:
// A-prefetch is float4, h-writes are 8B-packed.
// Grid = 16 with 8 inert blocks so partner pairs (bid, bid+8) land on the
// same XCD under the empirical bid%8 mapping (perf hint only; correctness
// never depends on placement).
// ---------------------------------------------------------------------------
__global__ __launch_bounds__(512, 2) void scan_split_kernel(
    const float* __restrict__ A,     // [T, B, H] fp32 (t-major, from REMAP GEMM)
    const float* __restrict__ W1,    // [H, E+H] fp32
    bf16* __restrict__ Hbf,          // [B, T, H] bf16  (also the exchange medium)
    int* __restrict__ flags)
{
  const int bid = blockIdx.x;
  int c, s;
  if (bid < 4)                   { c = bid;     s = 0; }
  else if (bid >= 8 && bid < 12) { c = bid - 8; s = 1; }
  else return;

  __shared__ __align__(16) bf16 hsm[16 * HPAD];   // full h_{t-1} row (both halves)

  const int tid   = threadIdx.x;
  const int col0  = s * HALF;
  const int pcol0 = (1 - s) * HALF;
  const int rb0   = c * 16;
  const int w     = tid >> 6, lane = tid & 63;
  const int q     = lane >> 4, nl = lane & 15;
  const int n0    = col0 + w * 32;        // wave's 2 tiles: n0, n0+16
  const int m_ex  = tid >> 5;             // exchange row 0..15
  const int j_ex  = tid & 31;             // exchange 8-col group 0..31

  int* myflag = flags + (c * 2 + s) * 32;
  int* paflag = flags + (c * 2 + (1 - s)) * 32;

  // ---- all W1h for this block's half -> 128 VGPRs/wave -------------------
  // Wreg[i][j]: A-operand frag, lane (q,nl) holds W1[n0+i*16+nl][E + kg*32 + q*8 + u]
  // j 0..7  -> own-half K   (kg = s*8 + j)
  // j 8..15 -> peer-half K  (kg = (1-s)*8 + j-8)
  bf16x8 Wreg[2][16];
#pragma unroll
  for (int i = 0; i < 2; ++i) {
    const float* wrow = W1 + (size_t)(n0 + i * 16 + nl) * (EDIM + HDIM) + EDIM + q * 8;
#pragma unroll
    for (int j = 0; j < 16; ++j) {
      int kg = (j < 8) ? (s * 8 + j) : ((1 - s) * 8 + (j - 8));
      const float* src = wrow + kg * 32;
      bf16x8 v;
#pragma unroll
      for (int u = 0; u < 8; ++u) v[u] = (bf16)src[u];
      Wreg[i][j] = v;
    }
  }

  // ---- prefetch A_0 (two float4 per thread; t-major A) -------------------
  f32x4 An[2];
  {
    const float* ap = A + ((size_t)(rb0 + nl)) * HDIM + n0 + q * 4;
    An[0] = *(const f32x4*)ap;
    An[1] = *(const f32x4*)(ap + 16);
  }

  f32x4 acc[2];

  for (int t = 0; t < T_STEPS; ++t) {
    // ---- acc init + issue A_{t+1} prefetch -------------------------------
    acc[0] = An[0];
    acc[1] = An[1];
    {
      int tn = (t + 1 < T_STEPS) ? t + 1 : 0;
      const float* ap = A + ((size_t)tn * BATCH + rb0 + nl) * HDIM + n0 + q * 4;
      An[0] = *(const f32x4*)ap;
      An[1] = *(const f32x4*)(ap + 16);
    }

    // ---- poll peer + issue agent-scope loads of peer h_{t-1} half --------
    unsigned long long p0 = 0, p1 = 0;
    if (t > 0) {
      while (__hip_atomic_load(paflag, __ATOMIC_RELAXED,
                               __HIP_MEMORY_SCOPE_AGENT) < t) {}
      unsigned long long* src = (unsigned long long*)(
          Hbf + ((size_t)(rb0 + m_ex) * T_STEPS + (t - 1)) * HDIM + pcol0 + j_ex * 8);
      p0 = __hip_atomic_load(src,     __ATOMIC_RELAXED, __HIP_MEMORY_SCOPE_AGENT);
      p1 = __hip_atomic_load(src + 1, __ATOMIC_RELAXED, __HIP_MEMORY_SCOPE_AGENT);
    }

    if (t > 0) {
      // ---- own-half K (locally produced; hides peer-load latency) --------
#pragma unroll
      for (int kk = 0; kk < 8; ++kk) {
        bf16x8 af = *(bf16x8*)&hsm[nl * HPAD + col0 + kk * 32 + q * 8];
        acc[0] = __builtin_amdgcn_mfma_f32_16x16x32_bf16(Wreg[0][kk], af, acc[0], 0, 0, 0);
        acc[1] = __builtin_amdgcn_mfma_f32_16x16x32_bf16(Wreg[1][kk], af, acc[1], 0, 0, 0);
      }
      // ---- stage peer half into hsm --------------------------------------
      {
        union { unsigned long long u[2]; bf16x8 v; } P;
        P.u[0] = p0; P.u[1] = p1;
        *(bf16x8*)&hsm[m_ex * HPAD + pcol0 + j_ex * 8] = P.v;
      }
      __syncthreads();
      // ---- peer-half K ---------------------------------------------------
#pragma unroll
      for (int kk = 0; kk < 8; ++kk) {
        bf16x8 af = *(bf16x8*)&hsm[nl * HPAD + pcol0 + kk * 32 + q * 8];
        acc[0] = __builtin_amdgcn_mfma_f32_16x16x32_bf16(Wreg[0][8 + kk], af, acc[0], 0, 0, 0);
        acc[1] = __builtin_amdgcn_mfma_f32_16x16x32_bf16(Wreg[1][8 + kk], af, acc[1], 0, 0, 0);
      }
    }

    // ---- relu + pack; write h_t to hsm (own half) + Hbf ------------------
#pragma unroll
    for (int i = 0; i < 2; ++i) {
      bf16x4 hv;
#pragma unroll
      for (int r = 0; r < 4; ++r) hv[r] = (bf16)fmaxf(acc[i][r], 0.0f);
      *(bf16x4*)&hsm[nl * HPAD + n0 + i * 16 + q * 4] = hv;
      *(bf16x4*)(Hbf + ((size_t)(rb0 + nl) * T_STEPS + t) * HDIM + n0 + i * 16 + q * 4) = hv;
    }

    __syncthreads();   // h_t in hsm own half visible; vmcnt drained (stores done)
    if (tid == 0) {
      __threadfence();
      __hip_atomic_fetch_add(myflag, 1, __ATOMIC_RELAXED,
                             __HIP_MEMORY_SCOPE_AGENT);
    }
  }
}

// ---------------------------------------------------------------------------
__global__ __launch_bounds__(256) void copy_hfinal_kernel(
    const bf16* __restrict__ Hbf, float* __restrict__ out)
{
  int i = blockIdx.x * blockDim.x + threadIdx.x;
  int b = i / HDIM, n = i % HDIM;
  out[i] = (float)Hbf[((size_t)b * T_STEPS + (T_STEPS - 1)) * HDIM + n];
}

extern "C" void kernel_launch(void* const* d_in, const int* in_sizes, int n_in,
                              void* d_out, int out_size, void* d_ws, size_t ws_size,
                              hipStream_t stream) {
  const float* x  = (const float*)d_in[0];
  const float* W1 = (const float*)d_in[1];
  const float* b1 = (const float*)d_in[2];
  const float* W2 = (const float*)d_in[3];
  const float* b2 = (const float*)d_in[4];

  float* out = (float*)d_out;
  float* A   = out;   // fp32 x-projection staged in d_out ([T,B,H] order);
                      // consumed by the scan before GEMM3 overwrites it

  bf16* Hbf  = (bf16*)d_ws;                                       // 32 MB
  int* flags = (int*)((char*)d_ws + (size_t)BATCH * T_STEPS * HDIM * 2);

  hipMemsetAsync(flags, 0, 8 * 32 * sizeof(int), stream);

  // 1) A = X @ W1[:, :E]^T + b1  (bf16 MFMA, fp32 out, rows remapped to [T,B])
  {
    dim3 grid(BATCH * T_STEPS / 128, HDIM / 128);
    gemm_mfma_kernel<float, true><<<grid, 256, 0, stream>>>(
        x, EDIM, W1, EDIM + HDIM, 0, b1, A, HDIM, EDIM);
  }

  // 2) scan: 8 active blocks (grid 16 for XCD pairing), W1h fully in regs
  scan_split_kernel<<<16, 512, 0, stream>>>(A, W1, Hbf, flags);

  // 3) outs = Hbf @ W2^T + b2 (overwrites the A staging area)
  {
    dim3 grid(BATCH * T_STEPS / 128, ODIM / 128);
    gemm_mfma_kernel<bf16, false><<<grid, 256, 0, stream>>>(
        Hbf, HDIM, W2, HDIM, 0, b2, out, ODIM, HDIM);
  }

  // 4) h_final tail
  copy_hfinal_kernel<<<(BATCH * HDIM) / 256, 256, 0, stream>>>(
      Hbf, out + (size_t)BATCH * T_STEPS * ODIM);
}